// Round 8
// baseline (121.484 us; speedup 1.0000x reference)
//
#include <hip/hip_runtime.h>
#include <hip/hip_bf16.h>

#define BB 16
#define LL 2048
#define DD 64
#define QSCALE 0.1803368801111602f  // log2(e)/8 : folds temperature + ln->log2 into Q

typedef __attribute__((ext_vector_type(8))) short short8t;
typedef __attribute__((ext_vector_type(4))) float f32x4;
typedef __attribute__((ext_vector_type(4))) unsigned short ushort4t;

__device__ __forceinline__ unsigned short f2bf(float x) {
  union { float f; unsigned int u; } c; c.f = x;
  unsigned int u = c.u;
  u += 0x7fffu + ((u >> 16) & 1u);   // RNE; inputs are finite
  return (unsigned short)(u >> 16);
}

// merged prep: 0..2047 Q scale+cvt | 2048..4095 K cvt | 4096..4607 vtrans V | 4608..4639 mask->bias
__global__ void prep(const float* __restrict__ q, const float* __restrict__ k,
                     const float* __restrict__ v, const int* __restrict__ pm,
                     unsigned short* __restrict__ Qb, unsigned short* __restrict__ Kb,
                     unsigned short* __restrict__ VT, float* __restrict__ biasF) {
  __shared__ unsigned short t[64][66];
  int bid = blockIdx.x;
  if (bid < 4096) {
    bool isQ = bid < 2048;
    const float* in = isQ ? q : k;
    unsigned short* outp = isQ ? Qb : Kb;
    float sc = isQ ? QSCALE : 1.0f;
    int i = (bid & 2047) * 1024 + threadIdx.x * 4;
    float4 v4 = *(const float4*)(in + i);
    ushort4t o;
    o.x = f2bf(v4.x * sc); o.y = f2bf(v4.y * sc);
    o.z = f2bf(v4.z * sc); o.w = f2bf(v4.w * sc);
    *(ushort4t*)(outp + i) = o;
  } else if (bid < 4608) {
    int vb = bid - 4096;
    int b = vb >> 5, j0 = (vb & 31) * 64;
    const float* src = v + ((size_t)b * LL + j0) * DD;
#pragma unroll
    for (int i = 0; i < 16; ++i) {
      int lin = i * 256 + threadIdx.x;
      int j = lin >> 6, d = lin & 63;
      t[j][d] = f2bf(src[lin]);
    }
    __syncthreads();
    unsigned short* dst = VT + (size_t)b * DD * LL;
#pragma unroll
    for (int i = 0; i < 16; ++i) {
      int lin = i * 256 + threadIdx.x;
      int d = lin >> 6, j = lin & 63;
      dst[(size_t)d * LL + j0 + j] = t[j][d];
    }
  } else {
    int idx = (bid - 4608) * 1024 + threadIdx.x * 4;
    int4 m4 = *(const int4*)(pm + idx);
    float4 o;
    o.x = m4.x ? -180.f : 0.f; o.y = m4.y ? -180.f : 0.f;
    o.z = m4.z ? -180.f : 0.f; o.w = m4.w ? -180.f : 0.f;
    *(float4*)(biasF + idx) = o;
  }
}

__device__ __forceinline__ void async_cp16(const unsigned short* src, unsigned short* dst_lds) {
  __builtin_amdgcn_global_load_lds(
      (const __attribute__((address_space(1))) unsigned int*)src,
      (__attribute__((address_space(3))) unsigned int*)dst_lds, 16, 0, 0);
}

// Block = 128 threads (2 waves) owning 16 q-rows; wave w covers k in [1024w, 1024w+1024)
// as 32 tiles of BK=32. Wave-private LDS 10KB (K 4K, V 4K, PF f32[16][32] 2K) -> 20KB/block
// -> 8 blocks/CU -> 4 waves/SIMD (the occupancy lever). ~3 barriers total.
__global__ void __launch_bounds__(128, 4)
attn_main(const unsigned short* __restrict__ Qb, const unsigned short* __restrict__ Kb,
          const unsigned short* __restrict__ VTb, const float* __restrict__ biasF,
          float* __restrict__ out, float* __restrict__ attn) {
  __shared__ __align__(16) unsigned short TB[2][5120];  // 20 KB

  const int tid = threadIdx.x;
  const int w = tid >> 6;
  const int l = tid & 63;
  const int l15 = l & 15;
  const int g = l >> 4;

  // XCD-bijective swizzle (2048 % 8 == 0): each XCD owns 256 consecutive ids = 2 batches
  const int swz = (blockIdx.x & 7) * 256 + (blockIdx.x >> 3);
  const int b = swz >> 7;
  const int q0 = (swz & 127) << 4;   // block's 16 q-rows

  unsigned short* KB = &TB[w][0];      // [32][64] bf16
  unsigned short* VB = &TB[w][2048];   // [64][32] bf16 (d-major slice)
  float* PF = (float*)&TB[w][4096];    // [16][32] f32

  const unsigned short* Kbb = Kb + (size_t)b * LL * DD;
  const unsigned short* VTbb = VTb + (size_t)b * DD * LL;
  const float* biasb = biasF + b * LL;

  auto loadK = [&](int t) {   // tile t -> k0 = t*32
    const unsigned short* gs = Kbb + (size_t)(t * 32) * DD;
#pragma unroll
    for (int i2 = 0; i2 < 4; ++i2) {
      int row = i2 * 8 + (l >> 3);
      int ce = (l & 7) * 8;
      async_cp16(gs + row * 64 + (ce ^ ((row & 3) << 4)), KB + i2 * 512);
    }
  };
  auto loadV = [&](int t) {
    const int k0 = t * 32;
#pragma unroll
    for (int i2 = 0; i2 < 4; ++i2) {
      int row = i2 * 16 + (l >> 2);
      int ce = (l & 3) * 8;
      async_cp16(VTbb + (size_t)row * LL + k0 + (ce ^ ((row & 1) << 4)), VB + i2 * 512);
    }
  };

  // persistent Q fragments (both waves load same 16 rows): row = q0+l15, d = 32h+8g+e
  short8t qf[2];
  {
    const unsigned short* qbase = Qb + ((size_t)b * LL + q0 + l15) * DD + 8 * g;
    qf[0] = *(const short8t*)(qbase);
    qf[1] = *(const short8t*)(qbase + 32);
  }

  const int tA = w * 32;   // this wave's first tile

  // ---------------- pass A: row sums of exp2(s + bias) over this wave's k-half ----------------
  float ls[4] = {0.f, 0.f, 0.f, 0.f};
  {
    loadK(tA);
    float b0c = biasb[tA * 32 + l15], b1c = biasb[tA * 32 + 16 + l15];
    asm volatile("s_waitcnt vmcnt(0)" ::: "memory");
    for (int j = 0; j < 32; ++j) {
      short8t kf[2][2];
#pragma unroll
      for (int ni = 0; ni < 2; ++ni)
#pragma unroll
        for (int h = 0; h < 2; ++h)
          kf[ni][h] = *(const short8t*)(KB + (16 * ni + l15) * 64 + ((32 * h + 8 * g) ^ ((l15 & 3) << 4)));
      asm volatile("s_waitcnt lgkmcnt(0)" ::: "memory");
      __builtin_amdgcn_sched_barrier(0);
      int tn = tA + ((j + 1) & 31);
      loadK(tn);
      float nb0 = biasb[tn * 32 + l15], nb1 = biasb[tn * 32 + 16 + l15];

      f32x4 sacc[2] = {};
      __builtin_amdgcn_s_setprio(1);
#pragma unroll
      for (int ni = 0; ni < 2; ++ni)
#pragma unroll
        for (int h = 0; h < 2; ++h)
          sacc[ni] = __builtin_amdgcn_mfma_f32_16x16x32_bf16(qf[h], kf[ni][h], sacc[ni], 0, 0, 0);
      __builtin_amdgcn_s_setprio(0);
#pragma unroll
      for (int ni = 0; ni < 2; ++ni) {
        float bc = ni ? b1c : b0c;
#pragma unroll
        for (int r = 0; r < 4; ++r)
          ls[r] += exp2f(sacc[ni][r] + bc);
      }
      asm volatile("s_waitcnt vmcnt(0)" ::: "memory");
      __builtin_amdgcn_sched_barrier(0);
      b0c = nb0; b1c = nb1;
    }
  }

  // wave-local reduce over l15, then cross-wave (2 waves) via small LDS exchange
  float rinv_[4];
  {
#pragma unroll
    for (int r = 0; r < 4; ++r) {
      float s = ls[r];
      s += __shfl_xor(s, 1);
      s += __shfl_xor(s, 2);
      s += __shfl_xor(s, 4);
      s += __shfl_xor(s, 8);
      ls[r] = s;
    }
    float* exch = (float*)&TB[0][4096];  // wave0's PF region (unused yet)
    if (l15 == 0) {
#pragma unroll
      for (int r = 0; r < 4; ++r) exch[w * 16 + 4 * g + r] = ls[r];
    }
    __syncthreads();
#pragma unroll
    for (int r = 0; r < 4; ++r)
      rinv_[r] = 1.0f / (exch[4 * g + r] + exch[16 + 4 * g + r]);
    __syncthreads();  // exch consumed before wave0's PF writes in pass B
  }

  // ---------------- pass B: recompute S, write attn (full-line f32), O += P*V ----------------
  f32x4 oacc[4] = {};
  const size_t abase = (size_t)(b * LL + q0);
  {
    loadK(tA);
    loadV(tA);
    float b0c = biasb[tA * 32 + l15], b1c = biasb[tA * 32 + 16 + l15];
    asm volatile("s_waitcnt vmcnt(0)" ::: "memory");
    for (int j = 0; j < 32; ++j) {
      const int t = tA + j;
      const int k0 = t * 32;
      short8t kf[2][2], vf[4];
#pragma unroll
      for (int ni = 0; ni < 2; ++ni)
#pragma unroll
        for (int h = 0; h < 2; ++h)
          kf[ni][h] = *(const short8t*)(KB + (16 * ni + l15) * 64 + ((32 * h + 8 * g) ^ ((l15 & 3) << 4)));
#pragma unroll
      for (int ni = 0; ni < 4; ++ni)
        vf[ni] = *(const short8t*)(VB + (16 * ni + l15) * 32 + ((8 * g) ^ ((l & 1) << 4)));
      // fence: fragments register-resident before single-buffer restage (rule #18)
      asm volatile("s_waitcnt lgkmcnt(0)" ::: "memory");
      __builtin_amdgcn_sched_barrier(0);

      int tn = tA + ((j + 1) & 31);
      loadK(tn);
      loadV(tn);
      float nb0 = biasb[tn * 32 + l15], nb1 = biasb[tn * 32 + 16 + l15];

      f32x4 sacc[2] = {};
      __builtin_amdgcn_s_setprio(1);
#pragma unroll
      for (int ni = 0; ni < 2; ++ni)
#pragma unroll
        for (int h = 0; h < 2; ++h)
          sacc[ni] = __builtin_amdgcn_mfma_f32_16x16x32_bf16(qf[h], kf[ni][h], sacc[ni], 0, 0, 0);
      __builtin_amdgcn_s_setprio(0);

      // P -> PF f32 [16][32]; col XOR key(row) = ((row&3)<<3)^((row&4)<<2), row=4g+r
#pragma unroll
      for (int ni = 0; ni < 2; ++ni) {
        float bc = ni ? b1c : b0c;
#pragma unroll
        for (int r = 0; r < 4; ++r) {
          float p = exp2f(sacc[ni][r] + bc) * rinv_[r];
          PF[(4 * g + r) * 32 + ((16 * ni + l15) ^ (r << 3) ^ ((g & 1) << 4))] = p;
        }
      }

      // attn burst: 2 x float4 per lane; 4 lanes cover one 128B row-line
      {
        int row = l >> 2;
        int c0 = (l & 3) * 8;
        int key = ((row & 3) << 3) ^ ((row & 4) << 2);
        const float* src = PF + row * 32 + (c0 ^ key);
        f32x4 s0 = *(const f32x4*)(src);
        f32x4 s1 = *(const f32x4*)(src + 4);
        float* dst = attn + (abase + row) * LL + k0 + c0;
        *(f32x4*)(dst) = s0;
        *(f32x4*)(dst + 4) = s1;
      }

      // PV A-fragments from PF (f32 -> bf16 in regs): row = l15, k = 8g..8g+7
      short8t pfr;
      {
        int key = ((l15 & 3) << 3) ^ ((l15 & 4) << 2);
        const float* src = PF + l15 * 32 + ((8 * g) ^ key);
        f32x4 pa = *(const f32x4*)(src);
        f32x4 pb = *(const f32x4*)(src + 4);
        short8t f;
        f[0] = (short)f2bf(pa[0]); f[1] = (short)f2bf(pa[1]);
        f[2] = (short)f2bf(pa[2]); f[3] = (short)f2bf(pa[3]);
        f[4] = (short)f2bf(pb[0]); f[5] = (short)f2bf(pb[1]);
        f[6] = (short)f2bf(pb[2]); f[7] = (short)f2bf(pb[3]);
        pfr = f;
      }
      __builtin_amdgcn_s_setprio(1);
#pragma unroll
      for (int ni = 0; ni < 4; ++ni)
        oacc[ni] = __builtin_amdgcn_mfma_f32_16x16x32_bf16(pfr, vf[ni], oacc[ni], 0, 0, 0);
      __builtin_amdgcn_s_setprio(0);

      // counted: drain the 10 prefetch loads, keep our 2 attn stores in flight
      asm volatile("s_waitcnt vmcnt(2)" ::: "memory");
      __builtin_amdgcn_sched_barrier(0);
      b0c = nb0; b1c = nb1;
    }
  }

  // drain dangling glds before LDS reuse / kernel end
  asm volatile("s_waitcnt vmcnt(0)" ::: "memory");

  // cross-wave O reduction (2 waves, k-halves) via wave1's K region
  __syncthreads();
  float* Oex = (float*)&TB[1][0];  // 4 KB
  if (w == 1) {
#pragma unroll
    for (int ni = 0; ni < 4; ++ni)
#pragma unroll
      for (int r = 0; r < 4; ++r)
        Oex[(4 * g + r) * 64 + 16 * ni + l15] = oacc[ni][r];
  }
  __syncthreads();
  if (w == 0) {
#pragma unroll
    for (int ni = 0; ni < 4; ++ni)
#pragma unroll
      for (int r = 0; r < 4; ++r)
        out[(abase + 4 * g + r) * DD + 16 * ni + l15] =
            oacc[ni][r] + Oex[(4 * g + r) * 64 + 16 * ni + l15];
  }
}

extern "C" void kernel_launch(void* const* d_in, const int* in_sizes, int n_in,
                              void* d_out, int out_size, void* d_ws, size_t ws_size,
                              hipStream_t stream) {
  const float* q = (const float*)d_in[0];
  const float* k = (const float*)d_in[1];
  const float* v = (const float*)d_in[2];
  const int* pm = (const int*)d_in[3];

  float* out = (float*)d_out;
  float* attn = out + (size_t)BB * LL * DD;

  unsigned short* Qb = (unsigned short*)d_ws;
  unsigned short* Kb = Qb + (size_t)BB * LL * DD;
  unsigned short* VT = Kb + (size_t)BB * LL * DD;
  float* biasF = (float*)(VT + (size_t)BB * LL * DD);

  prep<<<4640, 256, 0, stream>>>(q, k, v, pm, Qb, Kb, VT, biasF);
  attn_main<<<2048, 128, 0, stream>>>(Qb, Kb, VT, biasF, out, attn);
}

// Round 9
// 91.587 us; speedup vs baseline: 1.3264x; 1.3264x over previous
//
#include <hip/hip_runtime.h>
#include <hip/hip_bf16.h>

#define BB 16
#define LL 2048
#define DD 64

typedef __attribute__((ext_vector_type(8))) short short8t;
typedef __attribute__((ext_vector_type(4))) float f32x4;
typedef __attribute__((ext_vector_type(4))) unsigned short ushort4t;

__device__ __forceinline__ unsigned short f2bf(float x) {
  union { float f; unsigned int u; } c; c.f = x;
  unsigned int u = c.u;
  u += 0x7fffu + ((u >> 16) & 1u);   // RNE; inputs are finite
  return (unsigned short)(u >> 16);
}

// fp32 -> bf16 elementwise (2M elements per tensor)
__global__ void cvt_bf16(const float* __restrict__ in, unsigned short* __restrict__ out) {
  int i = (blockIdx.x * 256 + threadIdx.x) * 4;
  float4 v = *(const float4*)(in + i);
  ushort4t o;
  o.x = f2bf(v.x); o.y = f2bf(v.y); o.z = f2bf(v.z); o.w = f2bf(v.w);
  *(ushort4t*)(out + i) = o;
}

// V [b][j][d] fp32 -> VT [b][d][j] bf16 (64x64 LDS tile transpose)
__global__ void vtrans(const float* __restrict__ v, unsigned short* __restrict__ vt) {
  __shared__ unsigned short t[64][66];
  int b = blockIdx.x >> 5, j0 = (blockIdx.x & 31) * 64;
  const float* src = v + ((size_t)b * LL + j0) * DD;
#pragma unroll
  for (int i = 0; i < 16; ++i) {
    int lin = i * 256 + threadIdx.x;
    int j = lin >> 6, d = lin & 63;
    t[j][d] = f2bf(src[lin]);
  }
  __syncthreads();
  unsigned short* dst = vt + (size_t)b * DD * LL;
#pragma unroll
  for (int i = 0; i < 16; ++i) {
    int lin = i * 256 + threadIdx.x;
    int d = lin >> 6, j = lin & 63;
    dst[(size_t)d * LL + j0 + j] = t[j][d];
  }
}

__device__ __forceinline__ void async_cp16(const unsigned short* src, unsigned short* dst_lds) {
  __builtin_amdgcn_global_load_lds(
      (const __attribute__((address_space(1))) unsigned int*)src,
      (__attribute__((address_space(3))) unsigned int*)dst_lds, 16, 0, 0);
}

// R5 structure: 4 waves, 64 queries/block; wave-private LDS (K dbuf, V fenced, PF f32).
// ONE change vs R5: attn store burst is NONTEMPORAL full-line float4 -> attn stream
// bypasses L2 allocation, so K/V working set stays L2-resident (anti-pollution).
__global__ void __launch_bounds__(256, 2)
attn_main(const unsigned short* __restrict__ Qb, const unsigned short* __restrict__ Kb,
          const unsigned short* __restrict__ VTb, const int* __restrict__ mask,
          float* __restrict__ out, float* __restrict__ attn) {
  __shared__ __align__(16) unsigned short TB[4][10240];
  float* redF = (float*)&TB[0][6144];
  float* rinvF = redF + 256;

  const int tid = threadIdx.x;
  const int w = tid >> 6;
  const int l = tid & 63;
  const int l15 = l & 15;
  const int g = l >> 4;

  const int swzb = (blockIdx.x & 7) * 64 + (blockIdx.x >> 3);
  const int b = swzb >> 5;
  const int q0 = (swzb & 31) << 6;

  unsigned short* K0 = &TB[w][0];
  unsigned short* K1 = &TB[w][2048];
  unsigned short* VB = &TB[w][4096];
  float* PF = (float*)&TB[w][6144];

  const unsigned short* Kbb = Kb + (size_t)b * LL * DD;
  const unsigned short* VTbb = VTb + (size_t)b * DD * LL;
  const int* maskb = mask + b * LL;

  auto loadK = [&](int k0, unsigned short* KB) {
    const unsigned short* gs = Kbb + (size_t)k0 * DD;
#pragma unroll
    for (int i2 = 0; i2 < 4; ++i2) {
      int row = i2 * 8 + (l >> 3);
      int ce = (l & 7) * 8;
      async_cp16(gs + row * 64 + (ce ^ ((row & 3) << 4)), KB + i2 * 512);
    }
  };
  auto loadV = [&](int k0) {
    const unsigned short* gs = VTbb + k0;
#pragma unroll
    for (int i2 = 0; i2 < 4; ++i2) {
      int row = i2 * 16 + (l >> 2);
      int ce = (l & 3) * 8;
      async_cp16(gs + (size_t)row * LL + (ce ^ ((row & 1) << 4)), VB + i2 * 512);
    }
  };

  short8t qf[4][2];
  {
    const unsigned short* qbase = Qb + ((size_t)b * LL + q0 + l15) * DD + 8 * g;
#pragma unroll
    for (int mi = 0; mi < 4; ++mi)
#pragma unroll
      for (int h = 0; h < 2; ++h)
        qf[mi][h] = *(const short8t*)(qbase + mi * 16 * DD + 32 * h);
  }

  float ls[4][4];
#pragma unroll
  for (int mi = 0; mi < 4; ++mi)
#pragma unroll
    for (int r = 0; r < 4; ++r) ls[mi][r] = 0.f;

  auto stepA = [&](int t, int tn, unsigned short* KBc, unsigned short* KBn,
                   int mk0c, int mk1c, int& mk0n, int& mk1n) {
    asm volatile("s_waitcnt vmcnt(0)" ::: "memory");
    loadK(tn * 32, KBn);
    mk0n = maskb[tn * 32 + l15];
    mk1n = maskb[tn * 32 + 16 + l15];

    short8t kf[2][2];
#pragma unroll
    for (int ni = 0; ni < 2; ++ni)
#pragma unroll
      for (int h = 0; h < 2; ++h) {
        int row = 16 * ni + l15;
        int col = (32 * h + 8 * g) ^ ((l15 & 3) << 4);
        kf[ni][h] = *(const short8t*)(KBc + row * 64 + col);
      }

    f32x4 sacc[4][2] = {};
    __builtin_amdgcn_s_setprio(1);
#pragma unroll
    for (int mi = 0; mi < 4; ++mi)
#pragma unroll
      for (int ni = 0; ni < 2; ++ni)
#pragma unroll
        for (int h = 0; h < 2; ++h)
          sacc[mi][ni] = __builtin_amdgcn_mfma_f32_16x16x32_bf16(qf[mi][h], kf[ni][h], sacc[mi][ni], 0, 0, 0);
    __builtin_amdgcn_s_setprio(0);
#pragma unroll
    for (int mi = 0; mi < 4; ++mi)
#pragma unroll
      for (int ni = 0; ni < 2; ++ni) {
        int mk = ni ? mk1c : mk0c;
#pragma unroll
        for (int r = 0; r < 4; ++r) {
          float p = mk ? 0.f : __expf(sacc[mi][ni][r] * 0.125f);
          ls[mi][r] += p;
        }
      }
  };

  {
    loadK(w * 32, K0);
    int a0 = maskb[w * 32 + l15], a1 = maskb[w * 32 + 16 + l15];
    int b0, b1;
    for (int j = 0; j < 8; ++j) {
      int t = w + 8 * j;
      stepA(t, t + 4, K0, K1, a0, a1, b0, b1);
      int t2 = t + 4;
      int tn = (j == 7) ? w : (t2 + 4);
      stepA(t2, tn, K1, K0, b0, b1, a0, a1);
    }
  }

#pragma unroll
  for (int mi = 0; mi < 4; ++mi)
#pragma unroll
    for (int r = 0; r < 4; ++r) {
      float s = ls[mi][r];
      s += __shfl_xor(s, 1);
      s += __shfl_xor(s, 2);
      s += __shfl_xor(s, 4);
      s += __shfl_xor(s, 8);
      if (l15 == 0) redF[w * 64 + 16 * mi + 4 * g + r] = s;
    }
  __syncthreads();
  if (tid < 64)
    rinvF[tid] = 1.0f / (redF[tid] + redF[64 + tid] + redF[128 + tid] + redF[192 + tid]);
  __syncthreads();

  float rinv_[4][4];
#pragma unroll
  for (int mi = 0; mi < 4; ++mi)
#pragma unroll
    for (int r = 0; r < 4; ++r) rinv_[mi][r] = rinvF[16 * mi + 4 * g + r];
  __syncthreads();

  f32x4 oacc[4][4] = {};
  const size_t arow = (size_t)b * LL + q0;
  auto stepB = [&](int t, int tn, const unsigned short* KBc, unsigned short* KBn,
                   int mk0c, int mk1c, int& mk0n, int& mk1n) {
    asm volatile("s_waitcnt vmcnt(8)" ::: "memory");
    const int k0 = t * 32;

    short8t kf[2][2], vf[4];
#pragma unroll
    for (int ni = 0; ni < 2; ++ni)
#pragma unroll
      for (int h = 0; h < 2; ++h) {
        int row = 16 * ni + l15;
        int col = (32 * h + 8 * g) ^ ((l15 & 3) << 4);
        kf[ni][h] = *(const short8t*)(KBc + row * 64 + col);
      }
#pragma unroll
    for (int ni = 0; ni < 4; ++ni)
      vf[ni] = *(const short8t*)(VB + (16 * ni + l15) * 32 + ((8 * g) ^ ((l & 1) << 4)));
    asm volatile("s_waitcnt lgkmcnt(0)" ::: "memory");
    __builtin_amdgcn_sched_barrier(0);

    loadK(tn * 32, KBn);
    mk0n = maskb[tn * 32 + l15];
    mk1n = maskb[tn * 32 + 16 + l15];
    loadV(tn * 32);

    f32x4 sacc[4][2] = {};
    __builtin_amdgcn_s_setprio(1);
#pragma unroll
    for (int mi = 0; mi < 4; ++mi)
#pragma unroll
      for (int ni = 0; ni < 2; ++ni)
#pragma unroll
        for (int h = 0; h < 2; ++h)
          sacc[mi][ni] = __builtin_amdgcn_mfma_f32_16x16x32_bf16(qf[mi][h], kf[ni][h], sacc[mi][ni], 0, 0, 0);
    __builtin_amdgcn_s_setprio(0);

#pragma unroll
    for (int mi = 0; mi < 4; ++mi)
#pragma unroll
      for (int ni = 0; ni < 2; ++ni) {
        int mk = ni ? mk1c : mk0c;
#pragma unroll
        for (int r = 0; r < 4; ++r) {
          float p = mk ? 0.f : __expf(sacc[mi][ni][r] * 0.125f) * rinv_[mi][r];
          PF[(16 * mi + 4 * g + r) * 32 + ((16 * ni + l15) ^ ((g & 1) << 4))] = p;
        }
      }

    // attn burst: 8 x float4 per lane, NONTEMPORAL (bypass L2 -> no K/V eviction)
#pragma unroll
    for (int it = 0; it < 8; ++it) {
      int row = it * 8 + (l >> 3);
      int c4 = (l & 7) * 4;
      f32x4 pv = *(const f32x4*)(PF + row * 32 + (c4 ^ (((row >> 2) & 1) << 4)));
      __builtin_nontemporal_store(pv, (f32x4*)(attn + (arow + row) * LL + k0 + c4));
    }

    short8t pf[4];
#pragma unroll
    for (int mi = 0; mi < 4; ++mi) {
      int qq = 16 * mi + l15;
      const float* src = PF + qq * 32 + ((8 * g) ^ (((l15 >> 2) & 1) << 4));
      float4 pa = *(const float4*)(src);
      float4 pb = *(const float4*)(src + 4);
      short8t f;
      f[0] = (short)f2bf(pa.x); f[1] = (short)f2bf(pa.y);
      f[2] = (short)f2bf(pa.z); f[3] = (short)f2bf(pa.w);
      f[4] = (short)f2bf(pb.x); f[5] = (short)f2bf(pb.y);
      f[6] = (short)f2bf(pb.z); f[7] = (short)f2bf(pb.w);
      pf[mi] = f;
    }
    __builtin_amdgcn_s_setprio(1);
#pragma unroll
    for (int mi = 0; mi < 4; ++mi)
#pragma unroll
      for (int ni = 0; ni < 4; ++ni)
        oacc[mi][ni] = __builtin_amdgcn_mfma_f32_16x16x32_bf16(pf[mi], vf[ni], oacc[mi][ni], 0, 0, 0);
    __builtin_amdgcn_s_setprio(0);
  };

  {
    loadK(w * 32, K0);
    int a0 = maskb[w * 32 + l15], a1 = maskb[w * 32 + 16 + l15];
    loadV(w * 32);
    asm volatile("s_waitcnt vmcnt(0)" ::: "memory");
    int b0, b1;
    for (int j = 0; j < 8; ++j) {
      int t = w + 8 * j;
      stepB(t, t + 4, K0, K1, a0, a1, b0, b1);
      int t2 = t + 4;
      int tn = (j == 7) ? w : (t2 + 4);
      stepB(t2, tn, K1, K0, b0, b1, a0, a1);
    }
  }

  asm volatile("s_waitcnt vmcnt(0)" ::: "memory");

  __syncthreads();
  float* OB = (float*)&TB[0][0];
  if (w) {
#pragma unroll
    for (int mi = 0; mi < 4; ++mi)
#pragma unroll
      for (int ni = 0; ni < 4; ++ni)
#pragma unroll
        for (int r = 0; r < 4; ++r)
          OB[(w - 1) * 4096 + (16 * mi + 4 * g + r) * 64 + 16 * ni + l15] = oacc[mi][ni][r];
  }
  __syncthreads();
  if (w == 0) {
#pragma unroll
    for (int mi = 0; mi < 4; ++mi)
#pragma unroll
      for (int ni = 0; ni < 4; ++ni)
#pragma unroll
        for (int r = 0; r < 4; ++r) {
          int pos = (16 * mi + 4 * g + r) * 64 + 16 * ni + l15;
          OB[12288 + pos] = oacc[mi][ni][r] + OB[pos] + OB[4096 + pos] + OB[8192 + pos];
        }
  }
  __syncthreads();
#pragma unroll
  for (int it = 0; it < 4; ++it) {
    int lin = it * 256 + tid;
    int row = lin >> 4;
    int c4 = (lin & 15) * 4;
    float4 o4 = *(const float4*)(OB + 12288 + row * 64 + c4);
    *(float4*)(out + ((size_t)(b * LL + q0 + row)) * DD + c4) = o4;
  }
}

extern "C" void kernel_launch(void* const* d_in, const int* in_sizes, int n_in,
                              void* d_out, int out_size, void* d_ws, size_t ws_size,
                              hipStream_t stream) {
  const float* q = (const float*)d_in[0];
  const float* k = (const float*)d_in[1];
  const float* v = (const float*)d_in[2];
  const int* pm = (const int*)d_in[3];

  float* out = (float*)d_out;
  float* attn = out + (size_t)BB * LL * DD;

  unsigned short* Qb = (unsigned short*)d_ws;
  unsigned short* Kb = Qb + (size_t)BB * LL * DD;
  unsigned short* VT = Kb + (size_t)BB * LL * DD;

  cvt_bf16<<<2048, 256, 0, stream>>>(q, Qb);
  cvt_bf16<<<2048, 256, 0, stream>>>(k, Kb);
  vtrans<<<512, 256, 0, stream>>>(v, VT);
  attn_main<<<512, 256, 0, stream>>>(Qb, Kb, VT, pm, out, attn);
}

// Round 10
// 91.550 us; speedup vs baseline: 1.3270x; 1.0004x over previous
//
#include <hip/hip_runtime.h>
#include <hip/hip_bf16.h>

#define BB 16
#define LL 2048
#define DD 64

typedef __attribute__((ext_vector_type(8))) short short8t;
typedef __attribute__((ext_vector_type(4))) float f32x4;
typedef __attribute__((ext_vector_type(4))) unsigned short ushort4t;

__device__ __forceinline__ unsigned short f2bf(float x) {
  union { float f; unsigned int u; } c; c.f = x;
  unsigned int u = c.u;
  u += 0x7fffu + ((u >> 16) & 1u);   // RNE; inputs are finite
  return (unsigned short)(u >> 16);
}

__device__ __forceinline__ int cvt_pk_bf16(float lo, float hi) {
  int r;
  asm("v_cvt_pk_bf16_f32 %0, %1, %2" : "=v"(r) : "v"(lo), "v"(hi));
  return r;
}

// fp32 -> bf16 elementwise (2M elements per tensor)
__global__ void cvt_bf16(const float* __restrict__ in, unsigned short* __restrict__ out) {
  int i = (blockIdx.x * 256 + threadIdx.x) * 4;
  float4 v = *(const float4*)(in + i);
  ushort4t o;
  o.x = f2bf(v.x); o.y = f2bf(v.y); o.z = f2bf(v.z); o.w = f2bf(v.w);
  *(ushort4t*)(out + i) = o;
}

// V [b][j][d] fp32 -> VT [b][d][j] bf16 (64x64 LDS tile transpose)
__global__ void vtrans(const float* __restrict__ v, unsigned short* __restrict__ vt) {
  __shared__ unsigned short t[64][66];
  int b = blockIdx.x >> 5, j0 = (blockIdx.x & 31) * 64;
  const float* src = v + ((size_t)b * LL + j0) * DD;
#pragma unroll
  for (int i = 0; i < 16; ++i) {
    int lin = i * 256 + threadIdx.x;
    int j = lin >> 6, d = lin & 63;
    t[j][d] = f2bf(src[lin]);
  }
  __syncthreads();
  unsigned short* dst = vt + (size_t)b * DD * LL;
#pragma unroll
  for (int i = 0; i < 16; ++i) {
    int lin = i * 256 + threadIdx.x;
    int d = lin >> 6, j = lin & 63;
    dst[(size_t)d * LL + j0 + j] = t[j][d];
  }
}

__device__ __forceinline__ void async_cp16(const unsigned short* src, unsigned short* dst_lds) {
  __builtin_amdgcn_global_load_lds(
      (const __attribute__((address_space(1))) unsigned int*)src,
      (__attribute__((address_space(3))) unsigned int*)dst_lds, 16, 0, 0);
}

// R5 structure + SWAPPED QK^T (mfma(K,Q)): P lands k-contiguous per lane ->
// attn stored as f32x4 straight from registers (no LDS round-trip); PV fragments
// via cvt_pk + tiny packed LDS transpose (8 b64 W + 4 b128 R, stride-20 pad).
// LDS 17KB/wave -> 69.6KB/block -> 2 blocks/CU.
__global__ void __launch_bounds__(256, 2)
attn_main(const unsigned short* __restrict__ Qb, const unsigned short* __restrict__ Kb,
          const unsigned short* __restrict__ VTb, const int* __restrict__ mask,
          float* __restrict__ out, float* __restrict__ attn) {
  __shared__ __align__(16) unsigned short TB[4][8704];  // K0,K1,V,P per wave (17KB)
  __shared__ float redF[256];
  __shared__ float rinvF[64];

  const int tid = threadIdx.x;
  const int w = tid >> 6;
  const int l = tid & 63;
  const int l15 = l & 15;
  const int g = l >> 4;

  const int swzb = (blockIdx.x & 7) * 64 + (blockIdx.x >> 3);
  const int b = swzb >> 5;
  const int q0 = (swzb & 31) << 6;

  unsigned short* K0 = &TB[w][0];
  unsigned short* K1 = &TB[w][2048];
  unsigned short* VB = &TB[w][4096];
  float* PW = (float*)&TB[w][6144];   // [4 mi][16 q][20 dw] packed bf16x2

  const unsigned short* Kbb = Kb + (size_t)b * LL * DD;
  const unsigned short* VTbb = VTb + (size_t)b * DD * LL;
  const int* maskb = mask + b * LL;

  auto loadK = [&](int k0, unsigned short* KB) {
    const unsigned short* gs = Kbb + (size_t)k0 * DD;
#pragma unroll
    for (int i2 = 0; i2 < 4; ++i2) {
      int row = i2 * 8 + (l >> 3);
      int ce = (l & 7) * 8;
      async_cp16(gs + row * 64 + (ce ^ ((row & 3) << 4)), KB + i2 * 512);
    }
  };
  auto loadV = [&](int k0) {
    const unsigned short* gs = VTbb + k0;
#pragma unroll
    for (int i2 = 0; i2 < 4; ++i2) {
      int row = i2 * 16 + (l >> 2);
      int ce = (l & 3) * 8;
      async_cp16(gs + (size_t)row * LL + (ce ^ ((row & 1) << 4)), VB + i2 * 512);
    }
  };

  // Q fragments (B-operand now; same layout): row q=q0+16mi+l15, d=32h+8g+e
  short8t qf[4][2];
  {
    const unsigned short* qbase = Qb + ((size_t)b * LL + q0 + l15) * DD + 8 * g;
#pragma unroll
    for (int mi = 0; mi < 4; ++mi)
#pragma unroll
      for (int h = 0; h < 2; ++h)
        qf[mi][h] = *(const short8t*)(qbase + mi * 16 * DD + 32 * h);
  }

  float ls[4] = {0.f, 0.f, 0.f, 0.f};

  // ---------------- pass A: row sums of exp(s); lane holds k=16ni+4g+r, q=16mi+l15 ----------------
  auto stepA = [&](int t, int tn, unsigned short* KBc, unsigned short* KBn,
                   const int4& m0c, const int4& m1c, int4& m0n, int4& m1n) {
    asm volatile("s_waitcnt vmcnt(0)" ::: "memory");
    loadK(tn * 32, KBn);
    m0n = *(const int4*)(maskb + tn * 32 + 4 * g);
    m1n = *(const int4*)(maskb + tn * 32 + 16 + 4 * g);

    short8t kf[2][2];
#pragma unroll
    for (int ni = 0; ni < 2; ++ni)
#pragma unroll
      for (int h = 0; h < 2; ++h) {
        int row = 16 * ni + l15;
        int col = (32 * h + 8 * g) ^ ((l15 & 3) << 4);
        kf[ni][h] = *(const short8t*)(KBc + row * 64 + col);
      }

    f32x4 sacc[4][2] = {};
    __builtin_amdgcn_s_setprio(1);
#pragma unroll
    for (int mi = 0; mi < 4; ++mi)
#pragma unroll
      for (int ni = 0; ni < 2; ++ni)
#pragma unroll
        for (int h = 0; h < 2; ++h)
          sacc[mi][ni] = __builtin_amdgcn_mfma_f32_16x16x32_bf16(kf[ni][h], qf[mi][h], sacc[mi][ni], 0, 0, 0);
    __builtin_amdgcn_s_setprio(0);
#pragma unroll
    for (int mi = 0; mi < 4; ++mi)
#pragma unroll
      for (int ni = 0; ni < 2; ++ni) {
        const int* mk = ni ? (const int*)&m1c : (const int*)&m0c;
#pragma unroll
        for (int r = 0; r < 4; ++r)
          ls[mi] += mk[r] ? 0.f : __expf(sacc[mi][ni][r] * 0.125f);
      }
  };

  {
    loadK(w * 32, K0);
    int4 a0 = *(const int4*)(maskb + w * 32 + 4 * g);
    int4 a1 = *(const int4*)(maskb + w * 32 + 16 + 4 * g);
    int4 b0, b1;
    for (int j = 0; j < 8; ++j) {
      int t = w + 8 * j;
      stepA(t, t + 4, K0, K1, a0, a1, b0, b1);
      int t2 = t + 4;
      int tn = (j == 7) ? w : (t2 + 4);
      stepA(t2, tn, K1, K0, b0, b1, a0, a1);
    }
  }

  // reduce over g-groups (k-direction is along lanes g now): xor16 + xor32
  {
#pragma unroll
    for (int mi = 0; mi < 4; ++mi) {
      float s = ls[mi];
      s += __shfl_xor(s, 16);
      s += __shfl_xor(s, 32);
      ls[mi] = s;
    }
    if (l < 16) {
#pragma unroll
      for (int mi = 0; mi < 4; ++mi) redF[w * 64 + 16 * mi + l] = ls[mi];
    }
  }
  __syncthreads();
  if (tid < 64)
    rinvF[tid] = 1.0f / (redF[tid] + redF[64 + tid] + redF[128 + tid] + redF[192 + tid]);
  __syncthreads();

  float rinv_[4];
#pragma unroll
  for (int mi = 0; mi < 4; ++mi) rinv_[mi] = rinvF[16 * mi + l15];

  // ---------------- pass B: recompute S, store attn from regs, PV via packed transpose ----------------
  f32x4 oacc[4][4] = {};
  const size_t arow = (size_t)b * LL + q0;
  auto stepB = [&](int t, int tn, const unsigned short* KBc, unsigned short* KBn,
                   const int4& m0c, const int4& m1c, int4& m0n, int4& m1n) {
    // drain prev 10 prefetch loads; keep prev 8 attn stores in flight
    asm volatile("s_waitcnt vmcnt(8)" ::: "memory");
    const int k0 = t * 32;

    short8t kf[2][2], vf[4];
#pragma unroll
    for (int ni = 0; ni < 2; ++ni)
#pragma unroll
      for (int h = 0; h < 2; ++h) {
        int row = 16 * ni + l15;
        int col = (32 * h + 8 * g) ^ ((l15 & 3) << 4);
        kf[ni][h] = *(const short8t*)(KBc + row * 64 + col);
      }
#pragma unroll
    for (int ni = 0; ni < 4; ++ni)
      vf[ni] = *(const short8t*)(VB + (16 * ni + l15) * 32 + ((8 * g) ^ ((l & 1) << 4)));
    // fence: fragments register-resident before single-buffer V restage (rule #18)
    asm volatile("s_waitcnt lgkmcnt(0)" ::: "memory");
    __builtin_amdgcn_sched_barrier(0);

    loadK(tn * 32, KBn);
    m0n = *(const int4*)(maskb + tn * 32 + 4 * g);
    m1n = *(const int4*)(maskb + tn * 32 + 16 + 4 * g);
    loadV(tn * 32);

    f32x4 sacc[4][2] = {};
    __builtin_amdgcn_s_setprio(1);
#pragma unroll
    for (int mi = 0; mi < 4; ++mi)
#pragma unroll
      for (int ni = 0; ni < 2; ++ni)
#pragma unroll
        for (int h = 0; h < 2; ++h)
          sacc[mi][ni] = __builtin_amdgcn_mfma_f32_16x16x32_bf16(kf[ni][h], qf[mi][h], sacc[mi][ni], 0, 0, 0);
    __builtin_amdgcn_s_setprio(0);

#pragma unroll
    for (int mi = 0; mi < 4; ++mi) {
      f32x4 pv0, pv1;
#pragma unroll
      for (int r = 0; r < 4; ++r) {
        pv0[r] = ((const int*)&m0c)[r] ? 0.f : __expf(sacc[mi][0][r] * 0.125f) * rinv_[mi];
        pv1[r] = ((const int*)&m1c)[r] ? 0.f : __expf(sacc[mi][1][r] * 0.125f) * rinv_[mi];
      }
      // attn store straight from registers: q=16mi+l15, k=k0+16ni+4g..+3
      float* dst = attn + (arow + 16 * mi + l15) * LL + k0 + 4 * g;
      *(f32x4*)(dst) = pv0;
      *(f32x4*)(dst + 16) = pv1;
      // pack for PV: dword m covers k=(2m,2m+1); lane writes m={2g,2g+1} and {8+2g,8+2g+1}
      int2 pa, pb;
      pa.x = cvt_pk_bf16(pv0[0], pv0[1]);
      pa.y = cvt_pk_bf16(pv0[2], pv0[3]);
      pb.x = cvt_pk_bf16(pv1[0], pv1[1]);
      pb.y = cvt_pk_bf16(pv1[2], pv1[3]);
      float* pwm = PW + mi * 320 + l15 * 20;
      *(int2*)(pwm + 2 * g) = pa;
      *(int2*)(pwm + 8 + 2 * g) = pb;
    }
    asm volatile("s_waitcnt lgkmcnt(0)" ::: "memory");
    __builtin_amdgcn_sched_barrier(0);

    // PV A-fragments: lane(l15,g) reads dwords m=4g..4g+3 -> k=8g..8g+7, row q=l15
    short8t pfr[4];
#pragma unroll
    for (int mi = 0; mi < 4; ++mi)
      pfr[mi] = *(const short8t*)(PW + mi * 320 + l15 * 20 + 4 * g);

    __builtin_amdgcn_s_setprio(1);
#pragma unroll
    for (int mi = 0; mi < 4; ++mi)
#pragma unroll
      for (int ni = 0; ni < 4; ++ni)
        oacc[mi][ni] = __builtin_amdgcn_mfma_f32_16x16x32_bf16(pfr[mi], vf[ni], oacc[mi][ni], 0, 0, 0);
    __builtin_amdgcn_s_setprio(0);
  };

  {
    loadK(w * 32, K0);
    int4 a0 = *(const int4*)(maskb + w * 32 + 4 * g);
    int4 a1 = *(const int4*)(maskb + w * 32 + 16 + 4 * g);
    loadV(w * 32);
    asm volatile("s_waitcnt vmcnt(0)" ::: "memory");
    int4 b0, b1;
    for (int j = 0; j < 8; ++j) {
      int t = w + 8 * j;
      stepB(t, t + 4, K0, K1, a0, a1, b0, b1);
      int t2 = t + 4;
      int tn = (j == 7) ? w : (t2 + 4);
      stepB(t2, tn, K1, K0, b0, b1, a0, a1);
    }
  }

  // drain tail prefetch glds + stores before LDS reuse
  asm volatile("s_waitcnt vmcnt(0)" ::: "memory");

  // cross-wave O reduction (waves held disjoint k-stripes); oacc layout unchanged
  __syncthreads();
  float* OB = (float*)&TB[0][0];
  if (w) {
#pragma unroll
    for (int mi = 0; mi < 4; ++mi)
#pragma unroll
      for (int ni = 0; ni < 4; ++ni)
#pragma unroll
        for (int r = 0; r < 4; ++r)
          OB[(w - 1) * 4096 + (16 * mi + 4 * g + r) * 64 + 16 * ni + l15] = oacc[mi][ni][r];
  }
  __syncthreads();
  if (w == 0) {
#pragma unroll
    for (int mi = 0; mi < 4; ++mi)
#pragma unroll
      for (int ni = 0; ni < 4; ++ni)
#pragma unroll
        for (int r = 0; r < 4; ++r) {
          int pos = (16 * mi + 4 * g + r) * 64 + 16 * ni + l15;
          OB[12288 + pos] = oacc[mi][ni][r] + OB[pos] + OB[4096 + pos] + OB[8192 + pos];
        }
  }
  __syncthreads();
#pragma unroll
  for (int it = 0; it < 4; ++it) {
    int lin = it * 256 + tid;
    int row = lin >> 4;
    int c4 = (lin & 15) * 4;
    float4 o4 = *(const float4*)(OB + 12288 + row * 64 + c4);
    *(float4*)(out + ((size_t)(b * LL + q0 + row)) * DD + c4) = o4;
  }
}

extern "C" void kernel_launch(void* const* d_in, const int* in_sizes, int n_in,
                              void* d_out, int out_size, void* d_ws, size_t ws_size,
                              hipStream_t stream) {
  const float* q = (const float*)d_in[0];
  const float* k = (const float*)d_in[1];
  const float* v = (const float*)d_in[2];
  const int* pm = (const int*)d_in[3];

  float* out = (float*)d_out;
  float* attn = out + (size_t)BB * LL * DD;

  unsigned short* Qb = (unsigned short*)d_ws;
  unsigned short* Kb = Qb + (size_t)BB * LL * DD;
  unsigned short* VT = Kb + (size_t)BB * LL * DD;

  cvt_bf16<<<2048, 256, 0, stream>>>(q, Qb);
  cvt_bf16<<<2048, 256, 0, stream>>>(k, Kb);
  vtrans<<<512, 256, 0, stream>>>(v, VT);
  attn_main<<<512, 256, 0, stream>>>(Qb, Kb, VT, pm, out, attn);
}